// Round 15
// baseline (164.694 us; speedup 1.0000x reference)
//
#include <hip/hip_runtime.h>
#include <float.h>

#define K_NN 10
#define BATCH 8
#define CIN 6
#define NPTS 4096
#define COUT 64
#define NSEG 8
#define SEGLEN (NPTS / NSEG)    // 512
#define CHUNK 16
#define NCHUNK (SEGLEN / CHUNK) // 32
#define NWORD (SEGLEN / 32)     // 16
#define NEG_SLOPE 0.2f
#define BN_EPS 1e-5f

// ---- workspace layout (bytes) ----
static constexpr size_t OFF_PTS  = 0;                                                    // float4[8*4096] (2x,2y,2z,|p|^2)
static constexpr size_t OFF_PTS2 = OFF_PTS + (size_t)BATCH * NPTS * sizeof(float4);      // float4[8*4096] (x3,x4,x5,0)
static constexpr size_t OFF_PTSP = OFF_PTS2 + (size_t)BATCH * NPTS * sizeof(float4);     // float4[8*4096] pair-interleaved
static constexpr size_t OFF_Q    = OFF_PTSP + (size_t)BATCH * NPTS * sizeof(float4);     // float[8*64*4096]
static constexpr size_t OFF_ST   = OFF_Q + (size_t)BATCH * COUT * NPTS * sizeof(float);  // double[27]

typedef float v2f __attribute__((ext_vector_type(2)));

// SESSION LEDGER (r0-r14): phase-A floor is NOT VALU count (r7/r10), occupancy
// (r3/r5), registers (r4), scalar-vs-LDS data path (r10==r11), LDS conflicts
// (0), launch envelopes (r13: worth ~2-4us), grid.sync (r12: >100us). r15
// tests the LAST named mechanism: the drain's serial dependent-load chain
// (clz->load->waitcnt->insert exposes full L1 latency per survivor; common to
// every 76-79/104us variant). Fix: 4-wide index extraction + 4 independent
// loads in flight. Selection order bit-identical.
__device__ __forceinline__ float wave_sum(float v) {
#pragma unroll
    for (int m = 32; m >= 1; m >>= 1) v += __shfl_xor(v, m, 64);
    return v;
}
__device__ __forceinline__ float wave_max(float v) {
#pragma unroll
    for (int m = 32; m >= 1; m >>= 1) v = fmaxf(v, __shfl_xor(v, m, 64));
    return v;
}

// pts stores (2x, 2y, 2z, ||p||^2); query coords pre-halved once per thread.
// d' = 2*inner - ||c||^2 -> 3 FMAs. Monotone shift of true distance, used
// consistently in knn/drain/merge. DO NOT reorder (bit-stable).
__device__ __forceinline__ float distp(float qx, float qy, float qz, float4 c) {
    return fmaf(c.x, qx, fmaf(c.y, qy, fmaf(c.z, qz, -c.w)));
}

// Packed pair distance (r7/r10-verified bit-identical to distp per element).
__device__ __forceinline__ v2f dist2(v2f qx2, v2f qy2, v2f qz2, float4 fa, float4 fb) {
    v2f cx = {fa.x, fa.y}, cy = {fa.z, fa.w}, cz = {fb.x, fb.y}, cw = {fb.z, fb.w};
#if __has_builtin(__builtin_elementwise_fma)
    v2f t = __builtin_elementwise_fma(cz, qz2, -cw);
    t = __builtin_elementwise_fma(cy, qy2, t);
    t = __builtin_elementwise_fma(cx, qx2, t);
    return t;
#else
    v2f t;
    t[0] = fmaf(cx[0], qx2[0], fmaf(cy[0], qy2[0], fmaf(cz[0], qz2[0], -cw[0])));
    t[1] = fmaf(cx[1], qx2[1], fmaf(cy[1], qy2[1], fmaf(cz[1], qz2[1], -cw[1])));
    return t;
#endif
}

__device__ __forceinline__ v2f vmax2(v2f a, v2f b) {
#if __has_builtin(__builtin_elementwise_max)
    return __builtin_elementwise_max(a, b);   // v_pk_max_f32
#else
    v2f r; r[0] = fmaxf(a[0], b[0]); r[1] = fmaxf(a[1], b[1]); return r;
#endif
}

// 10-deep chunk-max chain level
#define CHL(cj) { float _hi = fmaxf(cj, t); t = fminf(cj, t); cj = _hi; }

#define CSWP(va, vb, ia, ib) \
    if (va > vb) { float _tv = va; va = vb; vb = _tv; int _ti = ia; ia = ib; ib = _ti; }

#define INSERT10(dd, mm) \
    if ((dd) > v9) { \
        v9 = (dd); i9 = (mm); \
        CSWP(v9, v8, i9, i8) \
        CSWP(v8, v7, i8, i7) \
        CSWP(v7, v6, i7, i6) \
        CSWP(v6, v5, i6, i5) \
        CSWP(v5, v4, i5, i4) \
        CSWP(v4, v3, i4, i3) \
        CSWP(v3, v2, i3, i2) \
        CSWP(v2, v1, i2, i1) \
        CSWP(v1, v0, i1, i0) \
    }

// ---- Kernel P: pack pts / pts2 / ptsp (pair-interleaved); zero stats ----
__global__ __launch_bounds__(256) void prep_pts(const float* __restrict__ x,
                                                float4* __restrict__ pts,
                                                float4* __restrict__ pts2,
                                                float4* __restrict__ ptsp,
                                                double* __restrict__ stats) {
    if (blockIdx.x == 0 && threadIdx.x < 27) stats[threadIdx.x] = 0.0;
    int t = blockIdx.x * 256 + threadIdx.x;   // 0..32767
    int b = t >> 12;
    int n = t & (NPTS - 1);
    const float* xb = x + (size_t)b * CIN * NPTS;
    float X = xb[n];
    float Y = xb[NPTS + n];
    float Z = xb[2 * NPTS + n];
    float w = X * X + Y * Y + Z * Z;
    pts[t] = make_float4(2.0f * X, 2.0f * Y, 2.0f * Z, w);
    float x3 = xb[3 * NPTS + n];
    float x4 = xb[4 * NPTS + n];
    float x5 = xb[5 * NPTS + n];
    pts2[t] = make_float4(x3, x4, x5, 0.0f);
    // neighbor (n+1) via shuffle; even lanes write the pair record (n parity
    // == lane parity: shfl_down(1) valid). r7-verified.
    float Xn = __shfl_down(X, 1, 64);
    float Yn = __shfl_down(Y, 1, 64);
    float Zn = __shfl_down(Z, 1, 64);
    float wn = __shfl_down(w, 1, 64);
    if ((n & 1) == 0) {
        float4* pb = ptsp + (size_t)b * NPTS;
        pb[n]     = make_float4(2.0f * X, 2.0f * Xn, 2.0f * Y, 2.0f * Yn);
        pb[n + 1] = make_float4(2.0f * Z, 2.0f * Zn, w, wn);
    }
}

// ---- Kernel A: FUSED knn + merge + feat (LDS-staged candidates) ----
// Block = 8 waves x 64 queries.  Grid (NPTS/64, BATCH) = 512 blocks, 2/CU.
// Phase A: wave w stages its segment (pair format, 8KB) into its own LDS
//          slice, then packed threshold pass + packed bitmask pass
//          (v_pk_fma_f32) + BATCHED clz drain (r15: 4 independent loads in
//          flight per batch; ascending-index order preserved exactly).
// Phase B: publish per-wave top-10 into the OWN dead slice head; wave 0
//          merges 8x10 in (s asc, j asc) == ascending candidate order
//          (r3/r6/r8-proven tie semantics) -> idxL in LDS.
// Phase C: wave w computes q channels [8w,8w+8) via pts/pts2 float4 gathers;
//          wave 0 computes moment stats (64-query wave sums, double atomics).
__global__ __launch_bounds__(512, 4) void knnmf_kernel(const float4* __restrict__ pts,
                                                       const float4* __restrict__ pts2,
                                                       const float4* __restrict__ ptsp,
                                                       const float* __restrict__ W,
                                                       float* __restrict__ q,
                                                       double* __restrict__ stats) {
    __shared__ alignas(16) char smem[NSEG * SEGLEN * sizeof(float4)];  // 64 KB slices
    __shared__ unsigned short idxL[K_NN][64];        // 1.25 KB
    __shared__ float sW[COUT * CIN];                 // 1.5 KB
    __shared__ float sstat[27];

    for (int i = threadIdx.x; i < COUT * CIN; i += 512) sW[i] = W[i];

    int b  = blockIdx.y;
    int ln = threadIdx.x & 63;
    int wv = threadIdx.x >> 6;
    int wvu = __builtin_amdgcn_readfirstlane(wv);   // uniform (round-2 lesson)
    int n  = blockIdx.x * 64 + ln;
    const float4* p   = pts  + (size_t)b * NPTS;
    const float4* p2s = ptsp + (size_t)b * NPTS;
    float4 q4 = p[n];
    float qx = 0.5f * q4.x, qy = 0.5f * q4.y, qz = 0.5f * q4.z;
    v2f qx2 = {qx, qx}, qy2 = {qy, qy}, qz2 = {qz, qz};
    int m0 = wvu * SEGLEN;                          // UNIFORM segment base

    float4* slice = (float4*)(smem + (size_t)wvu * (SEGLEN * sizeof(float4)));

    // ---- stage segment wvu (pair format) into this wave's slice ----
    {
        const float4* src = p2s + m0;
#pragma unroll
        for (int i = 0; i < SEGLEN / 64; i++)
            slice[ln + 64 * i] = src[ln + 64 * i];
    }

    // ================= Phase A: knn body, segment wvu (LDS reads) ===========
    {
        // ---- pass 1: threshold from chunk maxima (packed, 8 pairs/chunk) ----
        float c0 = -FLT_MAX, c1 = -FLT_MAX, c2 = -FLT_MAX, c3 = -FLT_MAX, c4 = -FLT_MAX;
        float c5 = -FLT_MAX, c6 = -FLT_MAX, c7 = -FLT_MAX, c8 = -FLT_MAX, c9 = -FLT_MAX;

        for (int ch = 0; ch < NCHUNK; ch++) {
            const float4* cp = slice + ch * CHUNK;   // 16 float4 = 8 pairs (LDS)
            v2f e0 = dist2(qx2, qy2, qz2, cp[0],  cp[1]);
            v2f e1 = dist2(qx2, qy2, qz2, cp[2],  cp[3]);
            v2f e2 = dist2(qx2, qy2, qz2, cp[4],  cp[5]);
            v2f e3 = dist2(qx2, qy2, qz2, cp[6],  cp[7]);
            v2f e4 = dist2(qx2, qy2, qz2, cp[8],  cp[9]);
            v2f e5 = dist2(qx2, qy2, qz2, cp[10], cp[11]);
            v2f e6 = dist2(qx2, qy2, qz2, cp[12], cp[13]);
            v2f e7 = dist2(qx2, qy2, qz2, cp[14], cp[15]);
            v2f a0 = vmax2(e0, e1);
            v2f a1 = vmax2(e2, e3);
            v2f a2 = vmax2(e4, e5);
            v2f a3 = vmax2(e6, e7);
            v2f b0 = vmax2(a0, a1);
            v2f b1 = vmax2(a2, a3);
            v2f cm = vmax2(b0, b1);
            float t = fmaxf(cm[0], cm[1]);        // exact: max reorder-invariant
            CHL(c0) CHL(c1) CHL(c2) CHL(c3) CHL(c4)
            CHL(c5) CHL(c6) CHL(c7) CHL(c8) CHL(c9)
        }
        float thr = c9;   // 10th-largest chunk max (<= exact v10)

        // ---- pass 2 + drain: bitmask survivors (packed, LDS), exact insert ----
        float v0 = -FLT_MAX, v1 = -FLT_MAX, v2 = -FLT_MAX, v3 = -FLT_MAX, v4 = -FLT_MAX;
        float v5 = -FLT_MAX, v6 = -FLT_MAX, v7 = -FLT_MAX, v8 = -FLT_MAX, v9 = -FLT_MAX;
        int i0 = 0, i1 = 0, i2 = 0, i3 = 0, i4 = 0;
        int i5 = 0, i6 = 0, i7 = 0, i8 = 0, i9 = 0;

        for (int w = 0; w < NWORD; w++) {
            const float4* cp = slice + w * 32;    // 32 pts = 16 pairs (LDS)
            unsigned int mask = 0u;
#pragma unroll
            for (int pr = 0; pr < 16; pr++) {
                v2f d2v = dist2(qx2, qy2, qz2, cp[2 * pr], cp[2 * pr + 1]);
                // point 2pr -> higher bit, 2pr+1 -> lower: bit(31-u) = point u
                mask = (mask << 2) | (d2v[0] >= thr ? 2u : 0u) | (d2v[1] >= thr ? 1u : 0u);
            }
            int base = m0 + w * 32;
            // ---- r15 BATCHED drain: extract up to 4 indices (pure VALU,
            // MSB-first == ascending), issue 4 INDEPENDENT loads (4-deep
            // latency overlap vs the old serial clz->load->insert chain),
            // then guarded inserts in the SAME ascending order. Dummy slots
            // use j=31 (base+31 always < NPTS: load valid, insert skipped).
            while (mask) {
                int j0 = __builtin_clz(mask);
                unsigned r1 = mask ^ (0x80000000u >> j0);
                int n1 = (r1 != 0u);
                int j1 = n1 ? __builtin_clz(r1) : 31;
                unsigned r2 = n1 ? (r1 ^ (0x80000000u >> j1)) : 0u;
                int n2 = (r2 != 0u);
                int j2 = n2 ? __builtin_clz(r2) : 31;
                unsigned r3 = n2 ? (r2 ^ (0x80000000u >> j2)) : 0u;
                int n3 = (r3 != 0u);
                int j3 = n3 ? __builtin_clz(r3) : 31;
                mask = n3 ? (r3 ^ (0x80000000u >> j3)) : 0u;

                float4 gA = p[base + j0];         // 4 loads issued back-to-back
                float4 gB = p[base + j1];
                float4 gC = p[base + j2];
                float4 gD = p[base + j3];
                float dA = distp(qx, qy, qz, gA);
                float dB = distp(qx, qy, qz, gB);
                float dC = distp(qx, qy, qz, gC);
                float dD = distp(qx, qy, qz, gD);
                INSERT10(dA, base + j0)
                if (n1) { INSERT10(dB, base + j1) }
                if (n2) { INSERT10(dC, base + j2) }
                if (n3) { INSERT10(dD, base + j3) }
            }
        }

        // ---- publish into OWN slice head (slice is dead after drain) ----
        float* dpub = (float*)slice;                               // [10][64] f32
        unsigned short* ipub = (unsigned short*)((char*)slice + K_NN * 64 * sizeof(float));
        dpub[0 * 64 + ln] = v0; ipub[0 * 64 + ln] = (unsigned short)i0;
        dpub[1 * 64 + ln] = v1; ipub[1 * 64 + ln] = (unsigned short)i1;
        dpub[2 * 64 + ln] = v2; ipub[2 * 64 + ln] = (unsigned short)i2;
        dpub[3 * 64 + ln] = v3; ipub[3 * 64 + ln] = (unsigned short)i3;
        dpub[4 * 64 + ln] = v4; ipub[4 * 64 + ln] = (unsigned short)i4;
        dpub[5 * 64 + ln] = v5; ipub[5 * 64 + ln] = (unsigned short)i5;
        dpub[6 * 64 + ln] = v6; ipub[6 * 64 + ln] = (unsigned short)i6;
        dpub[7 * 64 + ln] = v7; ipub[7 * 64 + ln] = (unsigned short)i7;
        dpub[8 * 64 + ln] = v8; ipub[8 * 64 + ln] = (unsigned short)i8;
        dpub[9 * 64 + ln] = v9; ipub[9 * 64 + ln] = (unsigned short)i9;
    }
    __syncthreads();

    // ---- Phase B: wave 0 merges 8x10 -> idxL (s asc, j asc order) ----
    if (wvu == 0) {
        float v0 = -FLT_MAX, v1 = -FLT_MAX, v2 = -FLT_MAX, v3 = -FLT_MAX, v4 = -FLT_MAX;
        float v5 = -FLT_MAX, v6 = -FLT_MAX, v7 = -FLT_MAX, v8 = -FLT_MAX, v9 = -FLT_MAX;
        int i0 = 0, i1 = 0, i2 = 0, i3 = 0, i4 = 0;
        int i5 = 0, i6 = 0, i7 = 0, i8 = 0, i9 = 0;
#pragma unroll
        for (int w = 0; w < NSEG; w++) {
            const float* dp = (const float*)(smem + (size_t)w * (SEGLEN * sizeof(float4)));
            const unsigned short* ip = (const unsigned short*)((const char*)dp + K_NN * 64 * sizeof(float));
#pragma unroll
            for (int j = 0; j < K_NN; j++) {
                float d = dp[j * 64 + ln];
                int m = ip[j * 64 + ln];
                INSERT10(d, m)
            }
        }
        idxL[0][ln] = (unsigned short)i0;
        idxL[1][ln] = (unsigned short)i1;
        idxL[2][ln] = (unsigned short)i2;
        idxL[3][ln] = (unsigned short)i3;
        idxL[4][ln] = (unsigned short)i4;
        idxL[5][ln] = (unsigned short)i5;
        idxL[6][ln] = (unsigned short)i6;
        idxL[7][ln] = (unsigned short)i7;
        idxL[8][ln] = (unsigned short)i8;
        idxL[9][ln] = (unsigned short)i9;
    }
    __syncthreads();

    // ================= Phase C: feat (wave w -> channels [8w, 8w+8)) ========
    const float4* p2 = pts2 + (size_t)b * NPTS;

    int nb[K_NN];
#pragma unroll
    for (int k = 0; k < K_NN; k++) nb[k] = idxL[k][ln];

    float f[CIN][K_NN];
#pragma unroll
    for (int k = 0; k < K_NN; k++) {
        float4 c = p[nb[k]];                    // xyz in one 16B gather (doubled)
        f[0][k] = 0.5f * c.x; f[1][k] = 0.5f * c.y; f[2][k] = 0.5f * c.z;
    }
#pragma unroll
    for (int k = 0; k < K_NN; k++) {
        float4 c2 = p2[nb[k]];                  // ch 3-5 in one 16B gather
        f[3][k] = c2.x; f[4][k] = c2.y; f[5][k] = c2.z;
    }

    // center xyz over k, scale by 10
#pragma unroll
    for (int c = 0; c < 3; c++) {
        float s = 0.f;
#pragma unroll
        for (int k = 0; k < K_NN; k++) s += f[c][k];
        float m = s / 10.0f;
#pragma unroll
        for (int k = 0; k < K_NN; k++) f[c][k] = (f[c][k] - m) * 10.0f;
    }

    // q[b,o,n] = max_k y, 8 channels per wave (same per-(o,n) op order)
    float* qb = q + (size_t)b * COUT * NPTS + n;
    int o0 = wvu * 8;
#pragma unroll
    for (int oo = 0; oo < 8; oo++) {
        int o = o0 + oo;
        float w0 = sW[o * 6 + 0], w1 = sW[o * 6 + 1], w2 = sW[o * 6 + 2];
        float w3 = sW[o * 6 + 3], w4 = sW[o * 6 + 4], w5 = sW[o * 6 + 5];
        float mx = -FLT_MAX;
#pragma unroll
        for (int k = 0; k < K_NN; k++) {
            float y = w0 * f[0][k] + w1 * f[1][k] + w2 * f[2][k] +
                      w3 * f[3][k] + w4 * f[4][k] + w5 * f[5][k];
            mx = fmaxf(mx, y);
        }
        qb[(size_t)o * NPTS] = mx;
    }

    // ---- stats: wave 0 only (64-query wave sums, double atomics) ----
    if (wvu == 0) {
        float s1[CIN];
#pragma unroll
        for (int c = 0; c < CIN; c++) {
            float s = 0.f;
#pragma unroll
            for (int k = 0; k < K_NN; k++) s += f[c][k];
            s1[c] = s;
        }
        float s2[21];
#pragma unroll
        for (int i = 0; i < 21; i++) s2[i] = 0.f;
#pragma unroll
        for (int k = 0; k < K_NN; k++) {
            int pp = 0;
#pragma unroll
            for (int c = 0; c < CIN; c++)
#pragma unroll
                for (int c2 = c; c2 < CIN; c2++) {
                    s2[pp] += f[c][k] * f[c2][k];
                    pp++;
                }
        }
#pragma unroll
        for (int c = 0; c < CIN; c++) s1[c] = wave_sum(s1[c]);
#pragma unroll
        for (int i = 0; i < 21; i++) s2[i] = wave_sum(s2[i]);

        if (ln == 0) {
#pragma unroll
            for (int c = 0; c < CIN; c++) sstat[c] = s1[c];
#pragma unroll
            for (int i = 0; i < 21; i++) sstat[6 + i] = s2[i];
        }
        // same-wave LDS write->read ordered by lgkmcnt (no barrier needed)
        if (ln < 27) atomicAdd(&stats[ln], (double)sstat[ln]);
    }
}

// ---- Kernel C: fold moments -> scale/shift (in-block); leaky; reduce max+mean ----
__global__ __launch_bounds__(256) void reduce_kernel(const float* __restrict__ q,
                                                     const double* __restrict__ stats,
                                                     const float* __restrict__ W,
                                                     const float* __restrict__ gamma,
                                                     const float* __restrict__ beta,
                                                     float* __restrict__ out) {
    int o = blockIdx.x;
    int b = blockIdx.y;

    __shared__ float s_sc, s_sh;
    if (threadIdx.x == 0) {
        const double minv = 1.0 / (double)((size_t)BATCH * NPTS * K_NN);
        double w[CIN];
#pragma unroll
        for (int c = 0; c < CIN; c++) w[c] = (double)W[o * CIN + c];
        double mu = 0.0;
#pragma unroll
        for (int c = 0; c < CIN; c++) mu += w[c] * stats[c];
        mu *= minv;
        double ey2 = 0.0;
        int pp = 6;
#pragma unroll
        for (int c = 0; c < CIN; c++)
#pragma unroll
            for (int c2 = c; c2 < CIN; c2++) {
                double v = w[c] * w[c2] * stats[pp];
                ey2 += (c2 == c) ? v : 2.0 * v;
                pp++;
            }
        ey2 *= minv;
        double var = ey2 - mu * mu;
        float scale = gamma[o] * rsqrtf((float)var + BN_EPS);
        float shift = beta[o] - (float)mu * scale;
        s_sc = scale;
        s_sh = shift;
    }
    __syncthreads();
    float scale = s_sc, shift = s_sh;

    const float* qp = q + ((size_t)b * COUT + o) * NPTS;
    float mx = -FLT_MAX, sm = 0.f;
    for (int i = threadIdx.x; i < NPTS; i += 256) {
        float z = scale * qp[i] + shift;
        z = (z >= 0.f) ? z : NEG_SLOPE * z;
        mx = fmaxf(mx, z);
        sm += z;
    }
    mx = wave_max(mx);
    sm = wave_sum(sm);
    __shared__ float smx[4], ssm2[4];
    int wv = threadIdx.x >> 6;
    int ln = threadIdx.x & 63;
    if (ln == 0) { smx[wv] = mx; ssm2[wv] = sm; }
    __syncthreads();
    if (threadIdx.x == 0) {
        float m = fmaxf(fmaxf(smx[0], smx[1]), fmaxf(smx[2], smx[3]));
        float s = ssm2[0] + ssm2[1] + ssm2[2] + ssm2[3];
        out[b * 2 * COUT + o] = m;
        out[b * 2 * COUT + COUT + o] = s * (1.0f / (float)NPTS);
    }
}

extern "C" void kernel_launch(void* const* d_in, const int* in_sizes, int n_in,
                              void* d_out, int out_size, void* d_ws, size_t ws_size,
                              hipStream_t stream) {
    const float* x     = (const float*)d_in[0];
    const float* W     = (const float*)d_in[1];
    const float* gamma = (const float*)d_in[2];
    const float* beta  = (const float*)d_in[3];
    float* out = (float*)d_out;

    char* ws = (char*)d_ws;
    float4* pts   = (float4*)(ws + OFF_PTS);
    float4* pts2  = (float4*)(ws + OFF_PTS2);
    float4* ptsp  = (float4*)(ws + OFF_PTSP);
    float*  q     = (float*)(ws + OFF_Q);
    double* stats = (double*)(ws + OFF_ST);

    prep_pts<<<BATCH * NPTS / 256, 256, 0, stream>>>(x, pts, pts2, ptsp, stats);
    knnmf_kernel<<<dim3(NPTS / 64, BATCH), 512, 0, stream>>>(pts, pts2, ptsp, W, q, stats);
    reduce_kernel<<<dim3(COUT, BATCH), 256, 0, stream>>>(q, stats, W, gamma, beta, out);
}

// Round 16
// 162.992 us; speedup vs baseline: 1.0104x; 1.0104x over previous
//
#include <hip/hip_runtime.h>
#include <float.h>

#define K_NN 10
#define BATCH 8
#define CIN 6
#define NPTS 4096
#define COUT 64
#define NSEG 8
#define SEGLEN (NPTS / NSEG)    // 512
#define CHUNK 16
#define NCHUNK (SEGLEN / CHUNK) // 32
#define NWORD (SEGLEN / 32)     // 16
#define NEG_SLOPE 0.2f
#define BN_EPS 1e-5f

// ---- workspace layout (bytes) ----
static constexpr size_t OFF_PTS  = 0;                                                    // float4[8*4096] (2x,2y,2z,|p|^2)
static constexpr size_t OFF_PTS2 = OFF_PTS + (size_t)BATCH * NPTS * sizeof(float4);      // float4[8*4096] (x3,x4,x5,0)
static constexpr size_t OFF_PTSP = OFF_PTS2 + (size_t)BATCH * NPTS * sizeof(float4);     // float4[8*4096] pair-interleaved
static constexpr size_t OFF_Q    = OFF_PTSP + (size_t)BATCH * NPTS * sizeof(float4);     // float[8*64*4096]
static constexpr size_t OFF_ST   = OFF_Q + (size_t)BATCH * COUT * NPTS * sizeof(float);  // double[27]

typedef float v2f __attribute__((ext_vector_type(2)));

// SESSION LEDGER (r0-r15) -- final. 197.5 -> 163.4 us (-17.3%). Wins: fused
// knn+merge+feat (r9, eliminated 21MB part/idx round-trip + 2 launches),
// packed v_pk_fma distances (r10), LDS-staged candidates (r11, neutral-time
// but freed the scalar pipe). Eliminated by direct experiment: VALU count
// (r7/r10: -25% insts, null), occupancy (r3/r5), registers (r4), scalar-vs-
// LDS path (r10==r11), LDS conflicts (0), launch envelopes (r13: ~2-4us),
// grid.sync (r12: >100us), drain load latency (r15: 4-wide batch, null).
// Phase-A floor ~104us is distributed issue-stall residue with no single
// HIP-source-addressable cause. This file == r14 (measured optimum).
__device__ __forceinline__ float wave_sum(float v) {
#pragma unroll
    for (int m = 32; m >= 1; m >>= 1) v += __shfl_xor(v, m, 64);
    return v;
}
__device__ __forceinline__ float wave_max(float v) {
#pragma unroll
    for (int m = 32; m >= 1; m >>= 1) v = fmaxf(v, __shfl_xor(v, m, 64));
    return v;
}

// pts stores (2x, 2y, 2z, ||p||^2); query coords pre-halved once per thread.
// d' = 2*inner - ||c||^2 -> 3 FMAs. Monotone shift of true distance, used
// consistently in knn/drain/merge. DO NOT reorder (bit-stable).
__device__ __forceinline__ float distp(float qx, float qy, float qz, float4 c) {
    return fmaf(c.x, qx, fmaf(c.y, qy, fmaf(c.z, qz, -c.w)));
}

// Packed pair distance (r7/r10-verified bit-identical to distp per element).
__device__ __forceinline__ v2f dist2(v2f qx2, v2f qy2, v2f qz2, float4 fa, float4 fb) {
    v2f cx = {fa.x, fa.y}, cy = {fa.z, fa.w}, cz = {fb.x, fb.y}, cw = {fb.z, fb.w};
#if __has_builtin(__builtin_elementwise_fma)
    v2f t = __builtin_elementwise_fma(cz, qz2, -cw);
    t = __builtin_elementwise_fma(cy, qy2, t);
    t = __builtin_elementwise_fma(cx, qx2, t);
    return t;
#else
    v2f t;
    t[0] = fmaf(cx[0], qx2[0], fmaf(cy[0], qy2[0], fmaf(cz[0], qz2[0], -cw[0])));
    t[1] = fmaf(cx[1], qx2[1], fmaf(cy[1], qy2[1], fmaf(cz[1], qz2[1], -cw[1])));
    return t;
#endif
}

__device__ __forceinline__ v2f vmax2(v2f a, v2f b) {
#if __has_builtin(__builtin_elementwise_max)
    return __builtin_elementwise_max(a, b);   // v_pk_max_f32
#else
    v2f r; r[0] = fmaxf(a[0], b[0]); r[1] = fmaxf(a[1], b[1]); return r;
#endif
}

// 10-deep chunk-max chain level
#define CHL(cj) { float _hi = fmaxf(cj, t); t = fminf(cj, t); cj = _hi; }

#define CSWP(va, vb, ia, ib) \
    if (va > vb) { float _tv = va; va = vb; vb = _tv; int _ti = ia; ia = ib; ib = _ti; }

#define INSERT10(dd, mm) \
    if ((dd) > v9) { \
        v9 = (dd); i9 = (mm); \
        CSWP(v9, v8, i9, i8) \
        CSWP(v8, v7, i8, i7) \
        CSWP(v7, v6, i7, i6) \
        CSWP(v6, v5, i6, i5) \
        CSWP(v5, v4, i5, i4) \
        CSWP(v4, v3, i4, i3) \
        CSWP(v3, v2, i3, i2) \
        CSWP(v2, v1, i2, i1) \
        CSWP(v1, v0, i1, i0) \
    }

// ---- Kernel P: pack pts / pts2 / ptsp (pair-interleaved); zero stats ----
__global__ __launch_bounds__(256) void prep_pts(const float* __restrict__ x,
                                                float4* __restrict__ pts,
                                                float4* __restrict__ pts2,
                                                float4* __restrict__ ptsp,
                                                double* __restrict__ stats) {
    if (blockIdx.x == 0 && threadIdx.x < 27) stats[threadIdx.x] = 0.0;
    int t = blockIdx.x * 256 + threadIdx.x;   // 0..32767
    int b = t >> 12;
    int n = t & (NPTS - 1);
    const float* xb = x + (size_t)b * CIN * NPTS;
    float X = xb[n];
    float Y = xb[NPTS + n];
    float Z = xb[2 * NPTS + n];
    float w = X * X + Y * Y + Z * Z;
    pts[t] = make_float4(2.0f * X, 2.0f * Y, 2.0f * Z, w);
    float x3 = xb[3 * NPTS + n];
    float x4 = xb[4 * NPTS + n];
    float x5 = xb[5 * NPTS + n];
    pts2[t] = make_float4(x3, x4, x5, 0.0f);
    // neighbor (n+1) via shuffle; even lanes write the pair record (n parity
    // == lane parity: shfl_down(1) valid). r7-verified.
    float Xn = __shfl_down(X, 1, 64);
    float Yn = __shfl_down(Y, 1, 64);
    float Zn = __shfl_down(Z, 1, 64);
    float wn = __shfl_down(w, 1, 64);
    if ((n & 1) == 0) {
        float4* pb = ptsp + (size_t)b * NPTS;
        pb[n]     = make_float4(2.0f * X, 2.0f * Xn, 2.0f * Y, 2.0f * Yn);
        pb[n + 1] = make_float4(2.0f * Z, 2.0f * Zn, w, wn);
    }
}

// ---- Kernel A: FUSED knn + merge + feat (LDS-staged candidates) ----
// Block = 8 waves x 64 queries.  Grid (NPTS/64, BATCH) = 512 blocks, 2/CU.
// Phase A: wave w stages its segment (pair format, 8KB) into its own LDS
//          slice via the vector path, then packed threshold pass + packed
//          bitmask pass (v_pk_fma_f32) + clz drain (divergent global reads
//          of pts, L1-hot). thr = 10th-largest of 32 chunk maxima <= v10;
//          survivor bitmask exact.
// Phase B: publish per-wave top-10 into the OWN dead slice head; wave 0
//          merges 8x10 in (s asc, j asc) == ascending candidate order
//          (r3/r6/r8-proven tie semantics) -> idxL in LDS.
// Phase C: wave w computes q channels [8w,8w+8) via pts/pts2 float4 gathers;
//          wave 0 computes moment stats (64-query wave sums, double atomics).
__global__ __launch_bounds__(512, 4) void knnmf_kernel(const float4* __restrict__ pts,
                                                       const float4* __restrict__ pts2,
                                                       const float4* __restrict__ ptsp,
                                                       const float* __restrict__ W,
                                                       float* __restrict__ q,
                                                       double* __restrict__ stats) {
    __shared__ alignas(16) char smem[NSEG * SEGLEN * sizeof(float4)];  // 64 KB slices
    __shared__ unsigned short idxL[K_NN][64];        // 1.25 KB
    __shared__ float sW[COUT * CIN];                 // 1.5 KB
    __shared__ float sstat[27];

    for (int i = threadIdx.x; i < COUT * CIN; i += 512) sW[i] = W[i];

    int b  = blockIdx.y;
    int ln = threadIdx.x & 63;
    int wv = threadIdx.x >> 6;
    int wvu = __builtin_amdgcn_readfirstlane(wv);   // uniform (round-2 lesson)
    int n  = blockIdx.x * 64 + ln;
    const float4* p   = pts  + (size_t)b * NPTS;
    const float4* p2s = ptsp + (size_t)b * NPTS;
    float4 q4 = p[n];
    float qx = 0.5f * q4.x, qy = 0.5f * q4.y, qz = 0.5f * q4.z;
    v2f qx2 = {qx, qx}, qy2 = {qy, qy}, qz2 = {qz, qz};
    int m0 = wvu * SEGLEN;                          // UNIFORM segment base

    float4* slice = (float4*)(smem + (size_t)wvu * (SEGLEN * sizeof(float4)));

    // ---- stage segment wvu (pair format) into this wave's slice ----
    // Coalesced vector loads (1KB/inst/wave); no barrier needed: same-wave
    // ds_write -> ds_read ordered by lgkmcnt.
    {
        const float4* src = p2s + m0;
#pragma unroll
        for (int i = 0; i < SEGLEN / 64; i++)
            slice[ln + 64 * i] = src[ln + 64 * i];
    }

    // ================= Phase A: knn body, segment wvu (LDS reads) ===========
    {
        // ---- pass 1: threshold from chunk maxima (packed, 8 pairs/chunk) ----
        float c0 = -FLT_MAX, c1 = -FLT_MAX, c2 = -FLT_MAX, c3 = -FLT_MAX, c4 = -FLT_MAX;
        float c5 = -FLT_MAX, c6 = -FLT_MAX, c7 = -FLT_MAX, c8 = -FLT_MAX, c9 = -FLT_MAX;

        for (int ch = 0; ch < NCHUNK; ch++) {
            const float4* cp = slice + ch * CHUNK;   // 16 float4 = 8 pairs (LDS)
            v2f e0 = dist2(qx2, qy2, qz2, cp[0],  cp[1]);
            v2f e1 = dist2(qx2, qy2, qz2, cp[2],  cp[3]);
            v2f e2 = dist2(qx2, qy2, qz2, cp[4],  cp[5]);
            v2f e3 = dist2(qx2, qy2, qz2, cp[6],  cp[7]);
            v2f e4 = dist2(qx2, qy2, qz2, cp[8],  cp[9]);
            v2f e5 = dist2(qx2, qy2, qz2, cp[10], cp[11]);
            v2f e6 = dist2(qx2, qy2, qz2, cp[12], cp[13]);
            v2f e7 = dist2(qx2, qy2, qz2, cp[14], cp[15]);
            v2f a0 = vmax2(e0, e1);
            v2f a1 = vmax2(e2, e3);
            v2f a2 = vmax2(e4, e5);
            v2f a3 = vmax2(e6, e7);
            v2f b0 = vmax2(a0, a1);
            v2f b1 = vmax2(a2, a3);
            v2f cm = vmax2(b0, b1);
            float t = fmaxf(cm[0], cm[1]);        // exact: max reorder-invariant
            CHL(c0) CHL(c1) CHL(c2) CHL(c3) CHL(c4)
            CHL(c5) CHL(c6) CHL(c7) CHL(c8) CHL(c9)
        }
        float thr = c9;   // 10th-largest chunk max (<= exact v10)

        // ---- pass 2 + drain: bitmask survivors (packed, LDS), exact insert ----
        float v0 = -FLT_MAX, v1 = -FLT_MAX, v2 = -FLT_MAX, v3 = -FLT_MAX, v4 = -FLT_MAX;
        float v5 = -FLT_MAX, v6 = -FLT_MAX, v7 = -FLT_MAX, v8 = -FLT_MAX, v9 = -FLT_MAX;
        int i0 = 0, i1 = 0, i2 = 0, i3 = 0, i4 = 0;
        int i5 = 0, i6 = 0, i7 = 0, i8 = 0, i9 = 0;

        for (int w = 0; w < NWORD; w++) {
            const float4* cp = slice + w * 32;    // 32 pts = 16 pairs (LDS)
            unsigned int mask = 0u;
#pragma unroll
            for (int pr = 0; pr < 16; pr++) {
                v2f d2v = dist2(qx2, qy2, qz2, cp[2 * pr], cp[2 * pr + 1]);
                // point 2pr -> higher bit, 2pr+1 -> lower: bit(31-u) = point u
                mask = (mask << 2) | (d2v[0] >= thr ? 2u : 0u) | (d2v[1] >= thr ? 1u : 0u);
            }
            int base = m0 + w * 32;
            while (mask) {
                int j = __builtin_clz(mask);        // MSB-first == ascending m
                mask ^= (0x80000000u >> j);
                int m = base + j;
                float4 cc = p[m];                   // divergent global, L1-hot
                float d = distp(qx, qy, qz, cc);
                INSERT10(d, m)
            }
        }

        // ---- publish into OWN slice head (slice is dead after drain) ----
        float* dpub = (float*)slice;                               // [10][64] f32
        unsigned short* ipub = (unsigned short*)((char*)slice + K_NN * 64 * sizeof(float));
        dpub[0 * 64 + ln] = v0; ipub[0 * 64 + ln] = (unsigned short)i0;
        dpub[1 * 64 + ln] = v1; ipub[1 * 64 + ln] = (unsigned short)i1;
        dpub[2 * 64 + ln] = v2; ipub[2 * 64 + ln] = (unsigned short)i2;
        dpub[3 * 64 + ln] = v3; ipub[3 * 64 + ln] = (unsigned short)i3;
        dpub[4 * 64 + ln] = v4; ipub[4 * 64 + ln] = (unsigned short)i4;
        dpub[5 * 64 + ln] = v5; ipub[5 * 64 + ln] = (unsigned short)i5;
        dpub[6 * 64 + ln] = v6; ipub[6 * 64 + ln] = (unsigned short)i6;
        dpub[7 * 64 + ln] = v7; ipub[7 * 64 + ln] = (unsigned short)i7;
        dpub[8 * 64 + ln] = v8; ipub[8 * 64 + ln] = (unsigned short)i8;
        dpub[9 * 64 + ln] = v9; ipub[9 * 64 + ln] = (unsigned short)i9;
    }
    __syncthreads();

    // ---- Phase B: wave 0 merges 8x10 -> idxL (s asc, j asc order) ----
    if (wvu == 0) {
        float v0 = -FLT_MAX, v1 = -FLT_MAX, v2 = -FLT_MAX, v3 = -FLT_MAX, v4 = -FLT_MAX;
        float v5 = -FLT_MAX, v6 = -FLT_MAX, v7 = -FLT_MAX, v8 = -FLT_MAX, v9 = -FLT_MAX;
        int i0 = 0, i1 = 0, i2 = 0, i3 = 0, i4 = 0;
        int i5 = 0, i6 = 0, i7 = 0, i8 = 0, i9 = 0;
#pragma unroll
        for (int w = 0; w < NSEG; w++) {
            const float* dp = (const float*)(smem + (size_t)w * (SEGLEN * sizeof(float4)));
            const unsigned short* ip = (const unsigned short*)((const char*)dp + K_NN * 64 * sizeof(float));
#pragma unroll
            for (int j = 0; j < K_NN; j++) {
                float d = dp[j * 64 + ln];
                int m = ip[j * 64 + ln];
                INSERT10(d, m)
            }
        }
        idxL[0][ln] = (unsigned short)i0;
        idxL[1][ln] = (unsigned short)i1;
        idxL[2][ln] = (unsigned short)i2;
        idxL[3][ln] = (unsigned short)i3;
        idxL[4][ln] = (unsigned short)i4;
        idxL[5][ln] = (unsigned short)i5;
        idxL[6][ln] = (unsigned short)i6;
        idxL[7][ln] = (unsigned short)i7;
        idxL[8][ln] = (unsigned short)i8;
        idxL[9][ln] = (unsigned short)i9;
    }
    __syncthreads();

    // ================= Phase C: feat (wave w -> channels [8w, 8w+8)) ========
    const float4* p2 = pts2 + (size_t)b * NPTS;

    int nb[K_NN];
#pragma unroll
    for (int k = 0; k < K_NN; k++) nb[k] = idxL[k][ln];

    float f[CIN][K_NN];
#pragma unroll
    for (int k = 0; k < K_NN; k++) {
        float4 c = p[nb[k]];                    // xyz in one 16B gather (doubled)
        f[0][k] = 0.5f * c.x; f[1][k] = 0.5f * c.y; f[2][k] = 0.5f * c.z;
    }
#pragma unroll
    for (int k = 0; k < K_NN; k++) {
        float4 c2 = p2[nb[k]];                  // ch 3-5 in one 16B gather
        f[3][k] = c2.x; f[4][k] = c2.y; f[5][k] = c2.z;
    }

    // center xyz over k, scale by 10
#pragma unroll
    for (int c = 0; c < 3; c++) {
        float s = 0.f;
#pragma unroll
        for (int k = 0; k < K_NN; k++) s += f[c][k];
        float m = s / 10.0f;
#pragma unroll
        for (int k = 0; k < K_NN; k++) f[c][k] = (f[c][k] - m) * 10.0f;
    }

    // q[b,o,n] = max_k y, 8 channels per wave (same per-(o,n) op order)
    float* qb = q + (size_t)b * COUT * NPTS + n;
    int o0 = wvu * 8;
#pragma unroll
    for (int oo = 0; oo < 8; oo++) {
        int o = o0 + oo;
        float w0 = sW[o * 6 + 0], w1 = sW[o * 6 + 1], w2 = sW[o * 6 + 2];
        float w3 = sW[o * 6 + 3], w4 = sW[o * 6 + 4], w5 = sW[o * 6 + 5];
        float mx = -FLT_MAX;
#pragma unroll
        for (int k = 0; k < K_NN; k++) {
            float y = w0 * f[0][k] + w1 * f[1][k] + w2 * f[2][k] +
                      w3 * f[3][k] + w4 * f[4][k] + w5 * f[5][k];
            mx = fmaxf(mx, y);
        }
        qb[(size_t)o * NPTS] = mx;
    }

    // ---- stats: wave 0 only (64-query wave sums, double atomics) ----
    if (wvu == 0) {
        float s1[CIN];
#pragma unroll
        for (int c = 0; c < CIN; c++) {
            float s = 0.f;
#pragma unroll
            for (int k = 0; k < K_NN; k++) s += f[c][k];
            s1[c] = s;
        }
        float s2[21];
#pragma unroll
        for (int i = 0; i < 21; i++) s2[i] = 0.f;
#pragma unroll
        for (int k = 0; k < K_NN; k++) {
            int pp = 0;
#pragma unroll
            for (int c = 0; c < CIN; c++)
#pragma unroll
                for (int c2 = c; c2 < CIN; c2++) {
                    s2[pp] += f[c][k] * f[c2][k];
                    pp++;
                }
        }
#pragma unroll
        for (int c = 0; c < CIN; c++) s1[c] = wave_sum(s1[c]);
#pragma unroll
        for (int i = 0; i < 21; i++) s2[i] = wave_sum(s2[i]);

        if (ln == 0) {
#pragma unroll
            for (int c = 0; c < CIN; c++) sstat[c] = s1[c];
#pragma unroll
            for (int i = 0; i < 21; i++) sstat[6 + i] = s2[i];
        }
        // same-wave LDS write->read ordered by lgkmcnt (no barrier needed)
        if (ln < 27) atomicAdd(&stats[ln], (double)sstat[ln]);
    }
}

// ---- Kernel C: fold moments -> scale/shift (in-block); leaky; reduce max+mean ----
__global__ __launch_bounds__(256) void reduce_kernel(const float* __restrict__ q,
                                                     const double* __restrict__ stats,
                                                     const float* __restrict__ W,
                                                     const float* __restrict__ gamma,
                                                     const float* __restrict__ beta,
                                                     float* __restrict__ out) {
    int o = blockIdx.x;
    int b = blockIdx.y;

    __shared__ float s_sc, s_sh;
    if (threadIdx.x == 0) {
        const double minv = 1.0 / (double)((size_t)BATCH * NPTS * K_NN);
        double w[CIN];
#pragma unroll
        for (int c = 0; c < CIN; c++) w[c] = (double)W[o * CIN + c];
        double mu = 0.0;
#pragma unroll
        for (int c = 0; c < CIN; c++) mu += w[c] * stats[c];
        mu *= minv;
        double ey2 = 0.0;
        int pp = 6;
#pragma unroll
        for (int c = 0; c < CIN; c++)
#pragma unroll
            for (int c2 = c; c2 < CIN; c2++) {
                double v = w[c] * w[c2] * stats[pp];
                ey2 += (c2 == c) ? v : 2.0 * v;
                pp++;
            }
        ey2 *= minv;
        double var = ey2 - mu * mu;
        float scale = gamma[o] * rsqrtf((float)var + BN_EPS);
        float shift = beta[o] - (float)mu * scale;
        s_sc = scale;
        s_sh = shift;
    }
    __syncthreads();
    float scale = s_sc, shift = s_sh;

    const float* qp = q + ((size_t)b * COUT + o) * NPTS;
    float mx = -FLT_MAX, sm = 0.f;
    for (int i = threadIdx.x; i < NPTS; i += 256) {
        float z = scale * qp[i] + shift;
        z = (z >= 0.f) ? z : NEG_SLOPE * z;
        mx = fmaxf(mx, z);
        sm += z;
    }
    mx = wave_max(mx);
    sm = wave_sum(sm);
    __shared__ float smx[4], ssm2[4];
    int wv = threadIdx.x >> 6;
    int ln = threadIdx.x & 63;
    if (ln == 0) { smx[wv] = mx; ssm2[wv] = sm; }
    __syncthreads();
    if (threadIdx.x == 0) {
        float m = fmaxf(fmaxf(smx[0], smx[1]), fmaxf(smx[2], smx[3]));
        float s = ssm2[0] + ssm2[1] + ssm2[2] + ssm2[3];
        out[b * 2 * COUT + o] = m;
        out[b * 2 * COUT + COUT + o] = s * (1.0f / (float)NPTS);
    }
}

extern "C" void kernel_launch(void* const* d_in, const int* in_sizes, int n_in,
                              void* d_out, int out_size, void* d_ws, size_t ws_size,
                              hipStream_t stream) {
    const float* x     = (const float*)d_in[0];
    const float* W     = (const float*)d_in[1];
    const float* gamma = (const float*)d_in[2];
    const float* beta  = (const float*)d_in[3];
    float* out = (float*)d_out;

    char* ws = (char*)d_ws;
    float4* pts   = (float4*)(ws + OFF_PTS);
    float4* pts2  = (float4*)(ws + OFF_PTS2);
    float4* ptsp  = (float4*)(ws + OFF_PTSP);
    float*  q     = (float*)(ws + OFF_Q);
    double* stats = (double*)(ws + OFF_ST);

    prep_pts<<<BATCH * NPTS / 256, 256, 0, stream>>>(x, pts, pts2, ptsp, stats);
    knnmf_kernel<<<dim3(NPTS / 64, BATCH), 512, 0, stream>>>(pts, pts2, ptsp, W, q, stats);
    reduce_kernel<<<dim3(COUT, BATCH), 256, 0, stream>>>(q, stats, W, gamma, beta, out);
}